// Round 19
// baseline (91.197 us; speedup 1.0000x reference)
//
#include <hip/hip_runtime.h>
#include <hip/hip_fp16.h>
#include <math.h>

#define HWN 9216   // 96*96
#define HD 96
#define WD 96

typedef _Float16 h8v __attribute__((ext_vector_type(8)));
typedef float f16x16 __attribute__((ext_vector_type(16)));

__device__ __forceinline__ ushort f2h(float f) {
  return __half_as_ushort(__float2half(f));
}
__device__ __forceinline__ __half2 u2h(unsigned u) {
  return __builtin_bit_cast(__half2, u);
}
__device__ __forceinline__ unsigned h2u(__half2 h) {
  return __builtin_bit_cast(unsigned, h);
}
__device__ __forceinline__ h8v u4h(uint4 v) {
  return __builtin_bit_cast(h8v, v);
}
__device__ __forceinline__ f16x16 mfma32(h8v a, h8v b, f16x16 c) {
  return __builtin_amdgcn_mfma_f32_32x32x16_f16(a, b, c, 0, 0, 0);
}
// packed f16 max (no __hmax2 in ROCm 7.2 headers) -> v_pk_max_f16
__device__ __forceinline__ __half2 pkmax2(__half2 a, __half2 b) {
  unsigned r;
  asm("v_pk_max_f16 %0, %1, %2" : "=v"(r) : "v"(h2u(a)), "v"(h2u(b)));
  return u2h(r);
}
__device__ __forceinline__ __half2 lrelu2(__half2 v, __half2 c02) {
  return pkmax2(v, __hmul2(v, c02));
}

// ---- zero the 8KB accumulator block (hipMemsetAsync costs ~40us in-graph; this ~2us) ----
__global__ __launch_bounds__(256) void zero_kernel(uint4* __restrict__ p) {
  p[threadIdx.x] = make_uint4(0, 0, 0, 0);
  p[256 + threadIdx.x] = make_uint4(0, 0, 0, 0);
}

// ---- fused: blocks 0..161 pack weights; blocks 162..545 transpose x + IN1 atomic stats ----
__global__ __launch_bounds__(256) void packxt_kernel(
    const float* __restrict__ w1, const float* __restrict__ wdef,
    const float* __restrict__ woff, const float* __restrict__ x,
    ushort* __restrict__ w1p, ushort* __restrict__ wdp, ushort* __restrict__ wofp,
    unsigned* __restrict__ xh, float* __restrict__ accS, float* __restrict__ accQ) {
  __shared__ float tl[128][97];
  int bid = blockIdx.x;
  int t = threadIdx.x;
  if (bid < 162) {
    int i = bid * 256 + t;
    const float* src;
    ushort* dst;
    int CT, CO_real, fi;
    if (i < 18432) { src = w1; dst = w1p; CT = 4; CO_real = 128; fi = i; }
    else if (i < 36864) { src = wdef; dst = wdp; CT = 4; CO_real = 128; fi = i - 18432; }
    else { src = woff; dst = wofp; CT = 1; CO_real = 27; fi = i - 36864; }
    int lane = fi & 63;
    int j = fi >> 6;
    int ks = j & 7; j >>= 3;
    int ct = j % CT;
    int kk = j / CT;
    int co = ct * 32 + (lane & 31);
    int c0 = ks * 16 + (lane >> 5) * 8;
    ushort fr[8];
#pragma unroll
    for (int e = 0; e < 8; ++e) {
      float v = 0.f;
      if (co < CO_real) v = src[(size_t)(co * 128 + c0 + e) * 9 + kk];
      fr[e] = f2h(v);
    }
    uint4 o4;
    o4.x = (unsigned)fr[0] | ((unsigned)fr[1] << 16);
    o4.y = (unsigned)fr[2] | ((unsigned)fr[3] << 16);
    o4.z = (unsigned)fr[4] | ((unsigned)fr[5] << 16);
    o4.w = (unsigned)fr[6] | ((unsigned)fr[7] << 16);
    *(uint4*)(dst + (size_t)fi * 8) = o4;
    return;
  }
  int xb = bid - 162;
  int b = xb / 96, y = xb % 96;
  const float* sbase = x + (size_t)b * 128 * HWN + y * WD;
  // float4-vectorized read: 24 float4 per channel row
  for (int i = t; i < 3072; i += 256) {
    int c = i / 24, j = i - c * 24;
    const float4 v = *(const float4*)(sbase + (size_t)c * HWN + j * 4);
    tl[c][j * 4 + 0] = v.x;
    tl[c][j * 4 + 1] = v.y;
    tl[c][j * 4 + 2] = v.z;
    tl[c][j * 4 + 3] = v.w;
  }
  __syncthreads();
  {
    int c = t >> 1, half = t & 1;
    float S = 0.f, Q = 0.f;
    for (int j = 0; j < 48; ++j) {
      float v = tl[c][half * 48 + j];
      S += v;
      Q += v * v;
    }
    S += __shfl_xor(S, 1, 64);
    Q += __shfl_xor(Q, 1, 64);
    if (half == 0) {
      atomicAdd(&accS[b * 128 + c], S);
      atomicAdd(&accQ[b * 128 + c], Q);
    }
  }
  unsigned* dbase = xh + (size_t)(b * 96 + y) * 96 * 64;
  for (int i = t; i < 6144; i += 256) {
    int xx = i >> 6, c2 = i & 63;
    unsigned lo = f2h(tl[2 * c2][xx]);
    unsigned hi = f2h(tl[2 * c2 + 1][xx]);
    dbase[xx * 64 + c2] = lo | (hi << 16);
  }
}

// ---- stats2: coalesced reduction over hBh (f16 ch-minor) -> atomic acc[b][128] ----
__global__ __launch_bounds__(256) void stats2_kernel(
    const ushort* __restrict__ hBh, float* __restrict__ accS,
    float* __restrict__ accQ) {
  int tile = blockIdx.x;  // 0..63, 144 pixels each
  int b = blockIdx.y;
  int t = threadIdx.x;
  int cc = t & 15, pp = t >> 4;  // chunk of 8 channels, pixel-in-group
  int wid = t >> 6, lane = t & 63;
  const ushort* base = hBh + ((size_t)b * HWN + tile * 144) * 128 + cc * 8;
  float S[8], Q[8];
#pragma unroll
  for (int e = 0; e < 8; ++e) { S[e] = 0.f; Q[e] = 0.f; }
  for (int i = 0; i < 9; ++i) {
    int pix = i * 16 + pp;
    uint4 v = *(const uint4*)(base + (size_t)pix * 128);
    unsigned ar[4] = {v.x, v.y, v.z, v.w};
#pragma unroll
    for (int j = 0; j < 4; ++j) {
      float2 f = __half22float2(u2h(ar[j]));
      S[2 * j] += f.x; Q[2 * j] += f.x * f.x;
      S[2 * j + 1] += f.y; Q[2 * j + 1] += f.y * f.y;
    }
  }
#pragma unroll
  for (int e = 0; e < 8; ++e) {
    S[e] += __shfl_xor(S[e], 16, 64); Q[e] += __shfl_xor(Q[e], 16, 64);
    S[e] += __shfl_xor(S[e], 32, 64); Q[e] += __shfl_xor(Q[e], 32, 64);
  }
  __shared__ float red[2][4][16][8];
  if (lane < 16) {
#pragma unroll
    for (int e = 0; e < 8; ++e) { red[0][wid][lane][e] = S[e]; red[1][wid][lane][e] = Q[e]; }
  }
  __syncthreads();
  if (t < 16) {
#pragma unroll
    for (int e = 0; e < 8; ++e) {
      float s = red[0][0][t][e] + red[0][1][t][e] + red[0][2][t][e] + red[0][3][t][e];
      float q = red[1][0][t][e] + red[1][1][t][e] + red[1][2][t][e] + red[1][3][t][e];
      atomicAdd(&accS[b * 128 + t * 8 + e], s);
      atomicAdd(&accQ[b * 128 + t * 8 + e], q);
    }
  }
}

// ---- conv1: in-block IN1 finalize (1KB acc read); 4 waves, both p-tiles per A-load ----
__global__ __launch_bounds__(256) void conv1_mfma(
    const ushort* __restrict__ inp, const float* __restrict__ accS,
    const float* __restrict__ accQ, const float* __restrict__ g1v,
    const float* __restrict__ b1v, const ushort* __restrict__ wp,
    const float* __restrict__ bias, ushort* __restrict__ outh) {
  __shared__ ushort halo[100 * 128];  // chunk-swizzled by (row&7)
  __shared__ __half2 sah[64], sbh[64];
  int b = blockIdx.y;
  int tile = blockIdx.x;
  int Y0 = (tile / 12) * 8, X0 = (tile % 12) * 8;
  int t = threadIdx.x;
  int lane = t & 63, ct = t >> 6;
  if (t < 64) {
    int c0 = 2 * t;
    float S0 = accS[b * 128 + c0], Q0 = accQ[b * 128 + c0];
    float S1 = accS[b * 128 + c0 + 1], Q1 = accQ[b * 128 + c0 + 1];
    float mu0 = S0 / (float)HWN, mu1 = S1 / (float)HWN;
    float rs0 = rsqrtf(Q0 / (float)HWN - mu0 * mu0 + 1e-5f);
    float rs1 = rsqrtf(Q1 / (float)HWN - mu1 * mu1 + 1e-5f);
    float a0 = rs0 * g1v[c0], a1 = rs1 * g1v[c0 + 1];
    sah[t] = __floats2half2_rn(a0, a1);
    sbh[t] = __floats2half2_rn(b1v[c0] - mu0 * a0, b1v[c0 + 1] - mu1 * a1);
  }
  __syncthreads();
  const __half2 c02 = __float2half2_rn(0.2f);
  const ushort* ib = inp + (size_t)b * HWN * 128;
  for (int i = t; i < 400; i += 256) {
    int r = i >> 2, q = i & 3;
    int gy = Y0 - 1 + r / 10, gx = X0 - 1 + r % 10;
    bool inb = ((unsigned)gy < 96u) && ((unsigned)gx < 96u);
    const uint4* gp4 = (const uint4*)(ib + (size_t)(gy * 96 + gx) * 128 + q * 32);
#pragma unroll
    for (int cc = 0; cc < 4; ++cc) {
      uint4 v = make_uint4(0, 0, 0, 0);
      if (inb) {
        uint4 g = gp4[cc];
        unsigned ar[4] = {g.x, g.y, g.z, g.w};
        int c2b = (q * 4 + cc) * 4;
#pragma unroll
        for (int j = 0; j < 4; ++j) {
          __half2 hv = __hfma2(u2h(ar[j]), sah[c2b + j], sbh[c2b + j]);
          hv = lrelu2(hv, c02);
          ar[j] = h2u(hv);
        }
        v.x = ar[0]; v.y = ar[1]; v.z = ar[2]; v.w = ar[3];
      }
      int ch = (q * 4 + cc) ^ (r & 7);
      *(uint4*)&halo[r * 128 + ch * 8] = v;
    }
  }
  __syncthreads();

  int pl = lane & 31, kh = lane >> 5;
  int p0 = pl, p1 = 32 + pl;
  f16x16 acc0 = (f16x16)(0.f), acc1 = (f16x16)(0.f);

  uint4 Acur[8], Anxt[8];
#pragma unroll
  for (int ks = 0; ks < 8; ++ks)
    Acur[ks] = *(const uint4*)(wp + (size_t)((0 * 4 + ct) * 8 + ks) * 512 + lane * 8);

  for (int kk = 0; kk < 9; ++kk) {
    if (kk < 8) {
#pragma unroll
      for (int ks = 0; ks < 8; ++ks)
        Anxt[ks] = *(const uint4*)(wp + (size_t)(((kk + 1) * 4 + ct) * 8 + ks) * 512 + lane * 8);
    }
    int ky = kk / 3, kx = kk % 3;
    int r0 = ((p0 >> 3) + ky) * 10 + (p0 & 7) + kx;
    int r1 = ((p1 >> 3) + ky) * 10 + (p1 & 7) + kx;
    __builtin_amdgcn_s_setprio(1);
#pragma unroll
    for (int ks = 0; ks < 8; ++ks) {
      int u0 = (ks * 2 + kh) ^ (r0 & 7);
      h8v bf0 = *(const h8v*)&halo[r0 * 128 + u0 * 8];
      acc0 = mfma32(u4h(Acur[ks]), bf0, acc0);
      int u1 = (ks * 2 + kh) ^ (r1 & 7);
      h8v bf1 = *(const h8v*)&halo[r1 * 128 + u1 * 8];
      acc1 = mfma32(u4h(Acur[ks]), bf1, acc1);
    }
    __builtin_amdgcn_s_setprio(0);
    if (kk < 8) {
#pragma unroll
      for (int ks = 0; ks < 8; ++ks) Acur[ks] = Anxt[ks];
    }
  }
  // epilogue: +bias, channel-minor f16 write (both p tiles)
#pragma unroll
  for (int pt = 0; pt < 2; ++pt) {
    int p = pt ? p1 : p0;
    const f16x16& acc = pt ? acc1 : acc0;
    int gp = (Y0 + (p >> 3)) * 96 + X0 + (p & 7);
#pragma unroll
    for (int g = 0; g < 4; ++g) {
      int ch0 = ct * 32 + 4 * kh + 8 * g;
      float v0 = acc[4 * g + 0] + bias[ch0 + 0];
      float v1 = acc[4 * g + 1] + bias[ch0 + 1];
      float v2 = acc[4 * g + 2] + bias[ch0 + 2];
      float v3 = acc[4 * g + 3] + bias[ch0 + 3];
      uint2 o;
      o.x = (unsigned)f2h(v0) | ((unsigned)f2h(v1) << 16);
      o.y = (unsigned)f2h(v2) | ((unsigned)f2h(v3) << 16);
      *(uint2*)&outh[((size_t)b * HWN + gp) * 128 + ch0] = o;
    }
  }
}

// helper: global chunk load + affine + lrelu (rare fallback path)
__device__ __forceinline__ uint4 gaffine(const ushort* hb, int pix, int cc,
                                         const __half2* sa2v, const __half2* sb2v,
                                         __half2 c02) {
  uint4 g = *(const uint4*)(hb + (size_t)pix * 128 + cc * 8);
  unsigned ar[4] = {g.x, g.y, g.z, g.w};
#pragma unroll
  for (int j = 0; j < 4; ++j) {
    __half2 hv = __hfma2(u2h(ar[j]), sa2v[j], sb2v[j]);
    hv = lrelu2(hv, c02);
    ar[j] = h2u(hv);
  }
  return make_uint4(ar[0], ar[1], ar[2], ar[3]);
}

// ---- fused deform: in-block IN2 finalize; 8x4 tiles, 4 waves; k-split offset conv;
//      S double-buffered -> ONE barrier per k ----
__global__ __launch_bounds__(256) void deform_fused(
    const ushort* __restrict__ h2n, const float* __restrict__ accS,
    const float* __restrict__ accQ, const float* __restrict__ g2v,
    const float* __restrict__ b2v, const ushort* __restrict__ wofp,
    const float* __restrict__ boff, const ushort* __restrict__ wdp,
    const float* __restrict__ x, float* __restrict__ out) {
  __shared__ __align__(16) ushort halo[96 * 128];   // 8 rows x 12 cols, chunk ^ (pix&15)
  __shared__ __align__(16) ushort S[2][32 * 128];   // dbuf [p][c], chunk ^ (p&15)
  __shared__ __align__(16) ushort4 idxs[9][32];
  __shared__ __align__(16) ushort4 wgtc[9][32];
  __shared__ __half2 sah[64], sbh[64];
  float* pf = (float*)S;  // phase-A partials [4 waves][32 co][32 p]; dead before S use
  int bid = blockIdx.x;
  int swz = (bid & 7) * 144 + (bid >> 3);  // bijective: 1152 % 8 == 0
  int b = swz / 288;
  int tile = swz % 288;
  int Y0 = (tile / 12) * 4, X0 = (tile % 12) * 8;
  int t = threadIdx.x;
  int lane = t & 63, w = t >> 6;
  const ushort* hb = h2n + (size_t)b * HWN * 128;
  if (t < 64) {
    int c0 = 2 * t;
    float S0 = accS[b * 128 + c0], Q0 = accQ[b * 128 + c0];
    float S1 = accS[b * 128 + c0 + 1], Q1 = accQ[b * 128 + c0 + 1];
    float mu0 = S0 / (float)HWN, mu1 = S1 / (float)HWN;
    float rs0 = rsqrtf(Q0 / (float)HWN - mu0 * mu0 + 1e-5f);
    float rs1 = rsqrtf(Q1 / (float)HWN - mu1 * mu1 + 1e-5f);
    float a0 = rs0 * g2v[c0], a1 = rs1 * g2v[c0 + 1];
    sah[t] = __floats2half2_rn(a0, a1);
    sbh[t] = __floats2half2_rn(b2v[c0] - mu0 * a0, b2v[c0 + 1] - mu1 * a1);
  }
  __syncthreads();
  const __half2 c02 = __float2half2_rn(0.2f);

  // halo staging: 96 pixels x 16 chunks, affine2+lrelu fused, swizzled
  for (int i = t; i < 1536; i += 256) {
    int pix = i >> 4, u = i & 15;
    int gy = Y0 - 2 + pix / 12, gx = X0 - 2 + pix % 12;
    uint4 v = make_uint4(0, 0, 0, 0);
    if (((unsigned)gy < 96u) && ((unsigned)gx < 96u)) {
      uint4 g = *(const uint4*)(hb + (size_t)(gy * 96 + gx) * 128 + u * 8);
      unsigned ar[4] = {g.x, g.y, g.z, g.w};
#pragma unroll
      for (int j = 0; j < 4; ++j) {
        __half2 hv = __hfma2(u2h(ar[j]), sah[u * 4 + j], sbh[u * 4 + j]);
        hv = lrelu2(hv, c02);
        ar[j] = h2u(hv);
      }
      v.x = ar[0]; v.y = ar[1]; v.z = ar[2]; v.w = ar[3];
    }
    *(uint4*)&halo[pix * 128 + ((u ^ (pix & 15)) * 8)] = v;
  }
  __syncthreads();

  // phase A: offset conv, k-split over ALL 4 waves (taps w, w+4, w+8)
  {
    int pl = lane & 31, kh = lane >> 5;
    int p = pl;
    f16x16 accm = (f16x16)(0.f);
    for (int kk = w; kk < 9; kk += 4) {
      int ky = kk / 3, kx = kk % 3;
      int hp = (1 + (p >> 3) + ky) * 12 + 1 + (p & 7) + kx;
#pragma unroll
      for (int ks = 0; ks < 8; ++ks) {
        uint4 a = *(const uint4*)(wofp + (size_t)(kk * 8 + ks) * 512 + lane * 8);
        int u = (ks * 2 + kh) ^ (hp & 15);
        h8v bf = *(const h8v*)&halo[hp * 128 + u * 8];
        accm = mfma32(u4h(a), bf, accm);
      }
    }
#pragma unroll
    for (int reg = 0; reg < 16; ++reg) {
      int co = 4 * kh + (reg & 3) + 8 * (reg >> 2);
      pf[(w * 32 + co) * 32 + p] = accm[reg];
    }
  }
  __syncthreads();

  // phase B: bilinear params for 9 taps x 32 pos (sums phase-A partials)
  for (int i = t; i < 288; i += 256) {
    int k = i >> 5, p = i & 31;
    int yy = Y0 + (p >> 3), xx = X0 + (p & 7);
    int cdy = 2 * k, cdx = 2 * k + 1, cm = 18 + k;
    float dy = pf[(0 * 32 + cdy) * 32 + p] + pf[(1 * 32 + cdy) * 32 + p] +
               pf[(2 * 32 + cdy) * 32 + p] + pf[(3 * 32 + cdy) * 32 + p] + boff[cdy];
    float dx = pf[(0 * 32 + cdx) * 32 + p] + pf[(1 * 32 + cdx) * 32 + p] +
               pf[(2 * 32 + cdx) * 32 + p] + pf[(3 * 32 + cdx) * 32 + p] + boff[cdx];
    float mv = pf[(0 * 32 + cm) * 32 + p] + pf[(1 * 32 + cm) * 32 + p] +
               pf[(2 * 32 + cm) * 32 + p] + pf[(3 * 32 + cm) * 32 + p] + boff[cm];
    float mask = 1.0f / (1.0f + expf(-mv));
    float py = dy + (float)(yy - 1 + (k / 3));
    float px = dx + (float)(xx - 1 + (k % 3));
    float fy = floorf(py), fx = floorf(px);
    float lyf = py - fy, lxf = px - fx;
    int y0 = (int)fy, x0 = (int)fx;
    int y1 = y0 + 1, x1 = x0 + 1;
    bool vy0 = (y0 >= 0) && (y0 < HD);
    bool vy1 = (y1 >= 0) && (y1 < HD);
    bool vx0 = (x0 >= 0) && (x0 < WD);
    bool vx1 = (x1 >= 0) && (x1 < WD);
    int y0c = min(max(y0, 0), HD - 1), y1c = min(max(y1, 0), HD - 1);
    int x0c = min(max(x0, 0), WD - 1), x1c = min(max(x1, 0), WD - 1);
    float w0 = (1.f - lyf) * (1.f - lxf) * ((vy0 && vx0) ? mask : 0.f);
    float w1v = (1.f - lyf) * lxf * ((vy0 && vx1) ? mask : 0.f);
    float w2 = lyf * (1.f - lxf) * ((vy1 && vx0) ? mask : 0.f);
    float w3 = lyf * lxf * ((vy1 && vx1) ? mask : 0.f);
    bool inh = (y0c >= Y0 - 2) && (y1c <= Y0 + 5) && (x0c >= X0 - 2) && (x1c <= X0 + 9);
    ushort4 sidx;
    if (inh) {
      int sy0 = y0c - (Y0 - 2), sy1 = y1c - (Y0 - 2);
      int sx0 = x0c - (X0 - 2), sx1 = x1c - (X0 - 2);
      sidx.x = (ushort)(sy0 * 12 + sx0);
      sidx.y = (ushort)(sy0 * 12 + sx1);
      sidx.z = (ushort)(sy1 * 12 + sx0);
      sidx.w = (ushort)(sy1 * 12 + sx1);
    } else {
      sidx.x = (ushort)((y0c * WD + x0c) | 0x8000);
      sidx.y = (ushort)(y0c * WD + x1c);
      sidx.z = (ushort)(y1c * WD + x0c);
      sidx.w = (ushort)(y1c * WD + x1c);
    }
    idxs[k][p] = sidx;
    ushort4 wc;
    wc.x = f2h(w0); wc.y = f2h(w1v); wc.z = f2h(w2); wc.w = f2h(w3);
    wgtc[k][p] = wc;
  }
  __syncthreads();

  int cc = t & 15;   // channel chunk (8 channels)
  int pp = t >> 4;   // 0..15; handles p = pp, pp+16
  int ct = w;        // wave = CO tile
  int pl = lane & 31, kh = lane >> 5;
  int pg = pl;
  f16x16 acc = (f16x16)(0.f);
  __half2 sa2v[4], sb2v[4];
#pragma unroll
  for (int j = 0; j < 4; ++j) { sa2v[j] = sah[cc * 4 + j]; sb2v[j] = sbh[cc * 4 + j]; }

  // prefetch residual x values (consumed in epilogue)
  int gp = (Y0 + (pg >> 3)) * 96 + X0 + (pg & 7);
  float xr[16];
#pragma unroll
  for (int reg = 0; reg < 16; ++reg) {
    int co = ct * 32 + 4 * kh + (reg & 3) + 8 * (reg >> 2);
    xr[reg] = x[(size_t)(b * 128 + co) * HWN + gp];
  }

  uint4 AW[8];
  for (int k = 0; k < 9; ++k) {
    const ushort* wk = wdp + (size_t)k * 16384;
#pragma unroll
    for (int ks = 0; ks < 8; ++ks)
      AW[ks] = *(const uint4*)(wk + (size_t)(ct * 8 + ks) * 512 + lane * 8);
    // blend from LDS halo (or rare global fallback) -> S[k&1]
    ushort* Sb_w = S[k & 1];
#pragma unroll
    for (int i2 = 0; i2 < 2; ++i2) {
      int p = pp + 16 * i2;
      ushort4 sidx = idxs[k][p];
      ushort4 wc = wgtc[k][p];
      uint4 C0, C1, C2, C3;
      if (sidx.x & 0x8000u) {
        C0 = gaffine(hb, sidx.x & 0x7fff, cc, sa2v, sb2v, c02);
        C1 = gaffine(hb, sidx.y, cc, sa2v, sb2v, c02);
        C2 = gaffine(hb, sidx.z, cc, sa2v, sb2v, c02);
        C3 = gaffine(hb, sidx.w, cc, sa2v, sb2v, c02);
      } else {
        C0 = *(const uint4*)&halo[sidx.x * 128 + ((cc ^ (sidx.x & 15)) * 8)];
        C1 = *(const uint4*)&halo[sidx.y * 128 + ((cc ^ (sidx.y & 15)) * 8)];
        C2 = *(const uint4*)&halo[sidx.z * 128 + ((cc ^ (sidx.z & 15)) * 8)];
        C3 = *(const uint4*)&halo[sidx.w * 128 + ((cc ^ (sidx.w & 15)) * 8)];
      }
      __half2 a0 = u2h((unsigned)wc.x * 0x10001u);
      __half2 a1 = u2h((unsigned)wc.y * 0x10001u);
      __half2 a2 = u2h((unsigned)wc.z * 0x10001u);
      __half2 a3 = u2h((unsigned)wc.w * 0x10001u);
      __half2 s0 = __hmul2(u2h(C0.x), a0);
      __half2 s1 = __hmul2(u2h(C0.y), a0);
      __half2 s2 = __hmul2(u2h(C0.z), a0);
      __half2 s3 = __hmul2(u2h(C0.w), a0);
      s0 = __hfma2(u2h(C1.x), a1, s0); s1 = __hfma2(u2h(C1.y), a1, s1);
      s2 = __hfma2(u2h(C1.z), a1, s2); s3 = __hfma2(u2h(C1.w), a1, s3);
      s0 = __hfma2(u2h(C2.x), a2, s0); s1 = __hfma2(u2h(C2.y), a2, s1);
      s2 = __hfma2(u2h(C2.z), a2, s2); s3 = __hfma2(u2h(C2.w), a2, s3);
      s0 = __hfma2(u2h(C3.x), a3, s0); s1 = __hfma2(u2h(C3.y), a3, s1);
      s2 = __hfma2(u2h(C3.z), a3, s2); s3 = __hfma2(u2h(C3.w), a3, s3);
      uint4 o4;
      o4.x = h2u(s0); o4.y = h2u(s1); o4.z = h2u(s2); o4.w = h2u(s3);
      *(uint4*)&Sb_w[p * 128 + ((cc ^ (p & 15)) * 8)] = o4;
    }
    asm volatile("s_waitcnt lgkmcnt(0)" ::: "memory");
    __builtin_amdgcn_s_barrier();
    // MFMA on S[k&1] (S[k&1] reuse fenced by the NEXT iteration's barrier)
    const ushort* Sb = S[k & 1];
    __builtin_amdgcn_s_setprio(1);
#pragma unroll
    for (int ks = 0; ks < 8; ++ks) {
      int u = (ks * 2 + kh) ^ (pg & 15);
      h8v bf = *(const h8v*)&Sb[pg * 128 + u * 8];
      acc = mfma32(u4h(AW[ks]), bf, acc);
    }
    __builtin_amdgcn_s_setprio(0);
  }
  // epilogue: residual + store (x already in regs)
#pragma unroll
  for (int reg = 0; reg < 16; ++reg) {
    int co = ct * 32 + 4 * kh + (reg & 3) + 8 * (reg >> 2);
    size_t oi = (size_t)(b * 128 + co) * HWN + gp;
    out[oi] = acc[reg] + xr[reg];
  }
}

extern "C" void kernel_launch(void* const* d_in, const int* in_sizes, int n_in,
                              void* d_out, int out_size, void* d_ws, size_t ws_size,
                              hipStream_t stream) {
  const float* x = (const float*)d_in[0];
  const float* g1 = (const float*)d_in[1];
  const float* b1 = (const float*)d_in[2];
  const float* g2 = (const float*)d_in[3];
  const float* b2 = (const float*)d_in[4];
  const float* w1 = (const float*)d_in[5];
  const float* bc1 = (const float*)d_in[6];
  const float* w_off = (const float*)d_in[7];
  const float* b_off = (const float*)d_in[8];
  const float* w_def = (const float*)d_in[9];
  float* out = (float*)d_out;
  float* ws = (float*)d_ws;

  // workspace layout (float units)
  ushort* w1p = (ushort*)ws;                   // 73728 f
  ushort* wofp = (ushort*)(ws + 73728);        // 18432 f
  ushort* wdp = (ushort*)(ws + 92160);         // 73728 f
  float* accS1 = ws + 165888;                  // 512
  float* accQ1 = ws + 166400;                  // 512
  float* accS2 = ws + 166912;                  // 512
  float* accQ2 = ws + 167424;                  // 512  (acc block: 2048 f = 8KB)
  ushort* xh = (ushort*)(ws + 167936);         // 2359296 f (raw x, ch-minor f16)
  ushort* hBh = (ushort*)(ws + 2527232);       // 2359296 f (conv1 out raw, ch-minor f16)

  zero_kernel<<<1, 256, 0, stream>>>((uint4*)accS1);
  packxt_kernel<<<546, 256, 0, stream>>>(w1, w_def, w_off, x, w1p, wdp, wofp,
                                         (unsigned*)xh, accS1, accQ1);
  conv1_mfma<<<dim3(144, 4), 256, 0, stream>>>(xh, accS1, accQ1, g1, b1, w1p, bc1, hBh);
  stats2_kernel<<<dim3(64, 4), 256, 0, stream>>>(hBh, accS2, accQ2);
  deform_fused<<<dim3(1152), 256, 0, stream>>>(hBh, accS2, accQ2, g2, b2, wofp, b_off,
                                               wdp, x, out);
}

// Round 20
// 79.170 us; speedup vs baseline: 1.1519x; 1.1519x over previous
//
#include <hip/hip_runtime.h>
#include <hip/hip_fp16.h>
#include <math.h>

#define HWN 9216   // 96*96
#define HD 96
#define WD 96

typedef _Float16 h8v __attribute__((ext_vector_type(8)));
typedef float f16x16 __attribute__((ext_vector_type(16)));

__device__ __forceinline__ ushort f2h(float f) {
  return __half_as_ushort(__float2half(f));
}
__device__ __forceinline__ __half2 u2h(unsigned u) {
  return __builtin_bit_cast(__half2, u);
}
__device__ __forceinline__ unsigned h2u(__half2 h) {
  return __builtin_bit_cast(unsigned, h);
}
__device__ __forceinline__ h8v u4h(uint4 v) {
  return __builtin_bit_cast(h8v, v);
}
__device__ __forceinline__ f16x16 mfma32(h8v a, h8v b, f16x16 c) {
  return __builtin_amdgcn_mfma_f32_32x32x16_f16(a, b, c, 0, 0, 0);
}
// packed f16 max (no __hmax2 in ROCm 7.2 headers) -> v_pk_max_f16
__device__ __forceinline__ __half2 pkmax2(__half2 a, __half2 b) {
  unsigned r;
  asm("v_pk_max_f16 %0, %1, %2" : "=v"(r) : "v"(h2u(a)), "v"(h2u(b)));
  return u2h(r);
}
__device__ __forceinline__ __half2 lrelu2(__half2 v, __half2 c02) {
  return pkmax2(v, __hmul2(v, c02));
}

// ---- fused: blocks 0..161 pack weights; blocks 162..545 transpose x + IN1 partials ----
__global__ __launch_bounds__(256) void packxt_kernel(
    const float* __restrict__ w1, const float* __restrict__ wdef,
    const float* __restrict__ woff, const float* __restrict__ x,
    ushort* __restrict__ w1p, ushort* __restrict__ wdp, ushort* __restrict__ wofp,
    unsigned* __restrict__ xh, float* __restrict__ partS, float* __restrict__ partQ) {
  __shared__ float tl[128][97];
  int bid = blockIdx.x;
  int t = threadIdx.x;
  if (bid < 162) {
    int i = bid * 256 + t;
    const float* src;
    ushort* dst;
    int CT, CO_real, fi;
    if (i < 18432) { src = w1; dst = w1p; CT = 4; CO_real = 128; fi = i; }
    else if (i < 36864) { src = wdef; dst = wdp; CT = 4; CO_real = 128; fi = i - 18432; }
    else { src = woff; dst = wofp; CT = 1; CO_real = 27; fi = i - 36864; }
    int lane = fi & 63;
    int j = fi >> 6;
    int ks = j & 7; j >>= 3;
    int ct = j % CT;
    int kk = j / CT;
    int co = ct * 32 + (lane & 31);
    int c0 = ks * 16 + (lane >> 5) * 8;
    ushort fr[8];
#pragma unroll
    for (int e = 0; e < 8; ++e) {
      float v = 0.f;
      if (co < CO_real) v = src[(size_t)(co * 128 + c0 + e) * 9 + kk];
      fr[e] = f2h(v);
    }
    uint4 o4;
    o4.x = (unsigned)fr[0] | ((unsigned)fr[1] << 16);
    o4.y = (unsigned)fr[2] | ((unsigned)fr[3] << 16);
    o4.z = (unsigned)fr[4] | ((unsigned)fr[5] << 16);
    o4.w = (unsigned)fr[6] | ((unsigned)fr[7] << 16);
    *(uint4*)(dst + (size_t)fi * 8) = o4;
    return;
  }
  int xb = bid - 162;
  int b = xb / 96, y = xb % 96;
  const float* sbase = x + (size_t)b * 128 * HWN + y * WD;
  // float4-vectorized read: 24 float4 per channel row
  for (int i = t; i < 3072; i += 256) {
    int c = i / 24, j = i - c * 24;
    const float4 v = *(const float4*)(sbase + (size_t)c * HWN + j * 4);
    tl[c][j * 4 + 0] = v.x;
    tl[c][j * 4 + 1] = v.y;
    tl[c][j * 4 + 2] = v.z;
    tl[c][j * 4 + 3] = v.w;
  }
  __syncthreads();
  {
    int c = t >> 1, half = t & 1;
    float S = 0.f, Q = 0.f;
    for (int j = 0; j < 48; ++j) {
      float v = tl[c][half * 48 + j];
      S += v;
      Q += v * v;
    }
    S += __shfl_xor(S, 1, 64);
    Q += __shfl_xor(Q, 1, 64);
    if (half == 0) {
      partS[((size_t)(b * 96 + y)) * 128 + c] = S;
      partQ[((size_t)(b * 96 + y)) * 128 + c] = Q;
    }
  }
  unsigned* dbase = xh + (size_t)(b * 96 + y) * 96 * 64;
  for (int i = t; i < 6144; i += 256) {
    int xx = i >> 6, c2 = i & 63;
    unsigned lo = f2h(tl[2 * c2][xx]);
    unsigned hi = f2h(tl[2 * c2 + 1][xx]);
    dbase[xx * 64 + c2] = lo | (hi << 16);
  }
}

// ---- finalize IN stats: partials -> (sa, sb); 512 blocks x 64 thr ----
__global__ __launch_bounds__(64) void finalize_kernel(
    const float* __restrict__ partS, const float* __restrict__ partQ,
    const float* __restrict__ gamma, const float* __restrict__ beta,
    float* __restrict__ sa_, float* __restrict__ sb_, int ntiles) {
  int bc = blockIdx.x;  // 0..511
  int b = bc >> 7, c = bc & 127;
  float S = 0.f, Q = 0.f;
  for (int tl = threadIdx.x; tl < ntiles; tl += 64) {
    S += partS[((size_t)b * ntiles + tl) * 128 + c];
    Q += partQ[((size_t)b * ntiles + tl) * 128 + c];
  }
#pragma unroll
  for (int off = 32; off > 0; off >>= 1) {
    S += __shfl_down(S, off, 64);
    Q += __shfl_down(Q, off, 64);
  }
  if (threadIdx.x == 0) {
    float mu = S / (float)HWN;
    float var = Q / (float)HWN - mu * mu;
    float rs = rsqrtf(var + 1e-5f);
    float a = rs * gamma[c];
    sa_[bc] = a;
    sb_[bc] = beta[c] - mu * a;
  }
}

// ---- stats2: coalesced reduction over hBh (f16 ch-minor) -> partials [b][64][128] ----
__global__ __launch_bounds__(256) void stats2_kernel(
    const ushort* __restrict__ hBh, float* __restrict__ partS,
    float* __restrict__ partQ) {
  int tile = blockIdx.x;  // 0..63, 144 pixels each
  int b = blockIdx.y;
  int t = threadIdx.x;
  int cc = t & 15, pp = t >> 4;  // chunk of 8 channels, pixel-in-group
  int wid = t >> 6, lane = t & 63;
  const ushort* base = hBh + ((size_t)b * HWN + tile * 144) * 128 + cc * 8;
  float S[8], Q[8];
#pragma unroll
  for (int e = 0; e < 8; ++e) { S[e] = 0.f; Q[e] = 0.f; }
  for (int i = 0; i < 9; ++i) {
    int pix = i * 16 + pp;
    uint4 v = *(const uint4*)(base + (size_t)pix * 128);
    unsigned ar[4] = {v.x, v.y, v.z, v.w};
#pragma unroll
    for (int j = 0; j < 4; ++j) {
      float2 f = __half22float2(u2h(ar[j]));
      S[2 * j] += f.x; Q[2 * j] += f.x * f.x;
      S[2 * j + 1] += f.y; Q[2 * j + 1] += f.y * f.y;
    }
  }
#pragma unroll
  for (int e = 0; e < 8; ++e) {
    S[e] += __shfl_xor(S[e], 16, 64); Q[e] += __shfl_xor(Q[e], 16, 64);
    S[e] += __shfl_xor(S[e], 32, 64); Q[e] += __shfl_xor(Q[e], 32, 64);
  }
  __shared__ float red[2][4][16][8];
  if (lane < 16) {
#pragma unroll
    for (int e = 0; e < 8; ++e) { red[0][wid][lane][e] = S[e]; red[1][wid][lane][e] = Q[e]; }
  }
  __syncthreads();
  if (t < 16) {
#pragma unroll
    for (int e = 0; e < 8; ++e) {
      float s = red[0][0][t][e] + red[0][1][t][e] + red[0][2][t][e] + red[0][3][t][e];
      float q = red[1][0][t][e] + red[1][1][t][e] + red[1][2][t][e] + red[1][3][t][e];
      partS[((size_t)b * 64 + tile) * 128 + t * 8 + e] = s;
      partQ[((size_t)b * 64 + tile) * 128 + t * 8 + e] = q;
    }
  }
}

// ---- conv1: 4 waves (w = ct), each wave does BOTH p-tiles per A-load ----
__global__ __launch_bounds__(256) void conv1_mfma(
    const ushort* __restrict__ inp, const float* __restrict__ sa_,
    const float* __restrict__ sb_, const ushort* __restrict__ wp,
    const float* __restrict__ bias, ushort* __restrict__ outh) {
  __shared__ ushort halo[100 * 128];  // chunk-swizzled by (row&7)
  __shared__ __half2 sah[64], sbh[64];
  int b = blockIdx.y;
  int tile = blockIdx.x;
  int Y0 = (tile / 12) * 8, X0 = (tile % 12) * 8;
  int t = threadIdx.x;
  int lane = t & 63, ct = t >> 6;
  if (t < 64) {
    sah[t] = __floats2half2_rn(sa_[b * 128 + 2 * t], sa_[b * 128 + 2 * t + 1]);
    sbh[t] = __floats2half2_rn(sb_[b * 128 + 2 * t], sb_[b * 128 + 2 * t + 1]);
  }
  __syncthreads();
  const __half2 c02 = __float2half2_rn(0.2f);
  const ushort* ib = inp + (size_t)b * HWN * 128;
  for (int i = t; i < 400; i += 256) {
    int r = i >> 2, q = i & 3;
    int gy = Y0 - 1 + r / 10, gx = X0 - 1 + r % 10;
    bool inb = ((unsigned)gy < 96u) && ((unsigned)gx < 96u);
    const uint4* gp4 = (const uint4*)(ib + (size_t)(gy * 96 + gx) * 128 + q * 32);
#pragma unroll
    for (int cc = 0; cc < 4; ++cc) {
      uint4 v = make_uint4(0, 0, 0, 0);
      if (inb) {
        uint4 g = gp4[cc];
        unsigned ar[4] = {g.x, g.y, g.z, g.w};
        int c2b = (q * 4 + cc) * 4;
#pragma unroll
        for (int j = 0; j < 4; ++j) {
          __half2 hv = __hfma2(u2h(ar[j]), sah[c2b + j], sbh[c2b + j]);
          hv = lrelu2(hv, c02);
          ar[j] = h2u(hv);
        }
        v.x = ar[0]; v.y = ar[1]; v.z = ar[2]; v.w = ar[3];
      }
      int ch = (q * 4 + cc) ^ (r & 7);
      *(uint4*)&halo[r * 128 + ch * 8] = v;
    }
  }
  __syncthreads();

  int pl = lane & 31, kh = lane >> 5;
  int p0 = pl, p1 = 32 + pl;
  f16x16 acc0 = (f16x16)(0.f), acc1 = (f16x16)(0.f);

  uint4 Acur[8], Anxt[8];
#pragma unroll
  for (int ks = 0; ks < 8; ++ks)
    Acur[ks] = *(const uint4*)(wp + (size_t)((0 * 4 + ct) * 8 + ks) * 512 + lane * 8);

  for (int kk = 0; kk < 9; ++kk) {
    if (kk < 8) {
#pragma unroll
      for (int ks = 0; ks < 8; ++ks)
        Anxt[ks] = *(const uint4*)(wp + (size_t)(((kk + 1) * 4 + ct) * 8 + ks) * 512 + lane * 8);
    }
    int ky = kk / 3, kx = kk % 3;
    int r0 = ((p0 >> 3) + ky) * 10 + (p0 & 7) + kx;
    int r1 = ((p1 >> 3) + ky) * 10 + (p1 & 7) + kx;
    __builtin_amdgcn_s_setprio(1);
#pragma unroll
    for (int ks = 0; ks < 8; ++ks) {
      int u0 = (ks * 2 + kh) ^ (r0 & 7);
      h8v bf0 = *(const h8v*)&halo[r0 * 128 + u0 * 8];
      acc0 = mfma32(u4h(Acur[ks]), bf0, acc0);
      int u1 = (ks * 2 + kh) ^ (r1 & 7);
      h8v bf1 = *(const h8v*)&halo[r1 * 128 + u1 * 8];
      acc1 = mfma32(u4h(Acur[ks]), bf1, acc1);
    }
    __builtin_amdgcn_s_setprio(0);
    if (kk < 8) {
#pragma unroll
      for (int ks = 0; ks < 8; ++ks) Acur[ks] = Anxt[ks];
    }
  }
  // epilogue: +bias, channel-minor f16 write (both p tiles)
#pragma unroll
  for (int pt = 0; pt < 2; ++pt) {
    int p = pt ? p1 : p0;
    const f16x16& acc = pt ? acc1 : acc0;
    int gp = (Y0 + (p >> 3)) * 96 + X0 + (p & 7);
#pragma unroll
    for (int g = 0; g < 4; ++g) {
      int ch0 = ct * 32 + 4 * kh + 8 * g;
      float v0 = acc[4 * g + 0] + bias[ch0 + 0];
      float v1 = acc[4 * g + 1] + bias[ch0 + 1];
      float v2 = acc[4 * g + 2] + bias[ch0 + 2];
      float v3 = acc[4 * g + 3] + bias[ch0 + 3];
      uint2 o;
      o.x = (unsigned)f2h(v0) | ((unsigned)f2h(v1) << 16);
      o.y = (unsigned)f2h(v2) | ((unsigned)f2h(v3) << 16);
      *(uint2*)&outh[((size_t)b * HWN + gp) * 128 + ch0] = o;
    }
  }
}

// helper: global chunk load + affine + lrelu (rare fallback path)
__device__ __forceinline__ uint4 gaffine(const ushort* hb, int pix, int cc,
                                         const __half2* sa2v, const __half2* sb2v,
                                         __half2 c02) {
  uint4 g = *(const uint4*)(hb + (size_t)pix * 128 + cc * 8);
  unsigned ar[4] = {g.x, g.y, g.z, g.w};
#pragma unroll
  for (int j = 0; j < 4; ++j) {
    __half2 hv = __hfma2(u2h(ar[j]), sa2v[j], sb2v[j]);
    hv = lrelu2(hv, c02);
    ar[j] = h2u(hv);
  }
  return make_uint4(ar[0], ar[1], ar[2], ar[3]);
}

// ---- fused deform: 8x4 tiles, 4 waves; offset-conv k-split over all waves;
//      S double-buffered -> ONE barrier per k ----
__global__ __launch_bounds__(256) void deform_fused(
    const ushort* __restrict__ h2n, const float* __restrict__ sa_,
    const float* __restrict__ sb_, const ushort* __restrict__ wofp,
    const float* __restrict__ boff, const ushort* __restrict__ wdp,
    const float* __restrict__ x, float* __restrict__ out) {
  __shared__ __align__(16) ushort halo[96 * 128];   // 8 rows x 12 cols, chunk ^ (pix&15)
  __shared__ __align__(16) ushort S[2][32 * 128];   // dbuf [p][c], chunk ^ (p&15)
  __shared__ __align__(16) ushort4 idxs[9][32];
  __shared__ __align__(16) ushort4 wgtc[9][32];
  __shared__ __half2 sah[64], sbh[64];
  float* pf = (float*)S;  // phase-A partials [4 waves][32 co][32 p]; dead before S use
  int bid = blockIdx.x;
  int swz = (bid & 7) * 144 + (bid >> 3);  // bijective: 1152 % 8 == 0
  int b = swz / 288;
  int tile = swz % 288;
  int Y0 = (tile / 12) * 4, X0 = (tile % 12) * 8;
  int t = threadIdx.x;
  int lane = t & 63, w = t >> 6;
  const ushort* hb = h2n + (size_t)b * HWN * 128;
  if (t < 64) {
    sah[t] = __floats2half2_rn(sa_[b * 128 + 2 * t], sa_[b * 128 + 2 * t + 1]);
    sbh[t] = __floats2half2_rn(sb_[b * 128 + 2 * t], sb_[b * 128 + 2 * t + 1]);
  }
  __syncthreads();
  const __half2 c02 = __float2half2_rn(0.2f);

  // halo staging: 96 pixels x 16 chunks, affine2+lrelu fused, swizzled
  for (int i = t; i < 1536; i += 256) {
    int pix = i >> 4, u = i & 15;
    int gy = Y0 - 2 + pix / 12, gx = X0 - 2 + pix % 12;
    uint4 v = make_uint4(0, 0, 0, 0);
    if (((unsigned)gy < 96u) && ((unsigned)gx < 96u)) {
      uint4 g = *(const uint4*)(hb + (size_t)(gy * 96 + gx) * 128 + u * 8);
      unsigned ar[4] = {g.x, g.y, g.z, g.w};
#pragma unroll
      for (int j = 0; j < 4; ++j) {
        __half2 hv = __hfma2(u2h(ar[j]), sah[u * 4 + j], sbh[u * 4 + j]);
        hv = lrelu2(hv, c02);
        ar[j] = h2u(hv);
      }
      v.x = ar[0]; v.y = ar[1]; v.z = ar[2]; v.w = ar[3];
    }
    *(uint4*)&halo[pix * 128 + ((u ^ (pix & 15)) * 8)] = v;
  }
  __syncthreads();

  // phase A: offset conv, k-split over ALL 4 waves (taps w, w+4, w+8)
  {
    int pl = lane & 31, kh = lane >> 5;
    int p = pl;
    f16x16 accm = (f16x16)(0.f);
    for (int kk = w; kk < 9; kk += 4) {
      int ky = kk / 3, kx = kk % 3;
      int hp = (1 + (p >> 3) + ky) * 12 + 1 + (p & 7) + kx;
#pragma unroll
      for (int ks = 0; ks < 8; ++ks) {
        uint4 a = *(const uint4*)(wofp + (size_t)(kk * 8 + ks) * 512 + lane * 8);
        int u = (ks * 2 + kh) ^ (hp & 15);
        h8v bf = *(const h8v*)&halo[hp * 128 + u * 8];
        accm = mfma32(u4h(a), bf, accm);
      }
    }
#pragma unroll
    for (int reg = 0; reg < 16; ++reg) {
      int co = 4 * kh + (reg & 3) + 8 * (reg >> 2);
      pf[(w * 32 + co) * 32 + p] = accm[reg];
    }
  }
  __syncthreads();

  // phase B: bilinear params for 9 taps x 32 pos (sums phase-A partials)
  for (int i = t; i < 288; i += 256) {
    int k = i >> 5, p = i & 31;
    int yy = Y0 + (p >> 3), xx = X0 + (p & 7);
    int cdy = 2 * k, cdx = 2 * k + 1, cm = 18 + k;
    float dy = pf[(0 * 32 + cdy) * 32 + p] + pf[(1 * 32 + cdy) * 32 + p] +
               pf[(2 * 32 + cdy) * 32 + p] + pf[(3 * 32 + cdy) * 32 + p] + boff[cdy];
    float dx = pf[(0 * 32 + cdx) * 32 + p] + pf[(1 * 32 + cdx) * 32 + p] +
               pf[(2 * 32 + cdx) * 32 + p] + pf[(3 * 32 + cdx) * 32 + p] + boff[cdx];
    float mv = pf[(0 * 32 + cm) * 32 + p] + pf[(1 * 32 + cm) * 32 + p] +
               pf[(2 * 32 + cm) * 32 + p] + pf[(3 * 32 + cm) * 32 + p] + boff[cm];
    float mask = 1.0f / (1.0f + expf(-mv));
    float py = dy + (float)(yy - 1 + (k / 3));
    float px = dx + (float)(xx - 1 + (k % 3));
    float fy = floorf(py), fx = floorf(px);
    float lyf = py - fy, lxf = px - fx;
    int y0 = (int)fy, x0 = (int)fx;
    int y1 = y0 + 1, x1 = x0 + 1;
    bool vy0 = (y0 >= 0) && (y0 < HD);
    bool vy1 = (y1 >= 0) && (y1 < HD);
    bool vx0 = (x0 >= 0) && (x0 < WD);
    bool vx1 = (x1 >= 0) && (x1 < WD);
    int y0c = min(max(y0, 0), HD - 1), y1c = min(max(y1, 0), HD - 1);
    int x0c = min(max(x0, 0), WD - 1), x1c = min(max(x1, 0), WD - 1);
    float w0 = (1.f - lyf) * (1.f - lxf) * ((vy0 && vx0) ? mask : 0.f);
    float w1v = (1.f - lyf) * lxf * ((vy0 && vx1) ? mask : 0.f);
    float w2 = lyf * (1.f - lxf) * ((vy1 && vx0) ? mask : 0.f);
    float w3 = lyf * lxf * ((vy1 && vx1) ? mask : 0.f);
    bool inh = (y0c >= Y0 - 2) && (y1c <= Y0 + 5) && (x0c >= X0 - 2) && (x1c <= X0 + 9);
    ushort4 sidx;
    if (inh) {
      int sy0 = y0c - (Y0 - 2), sy1 = y1c - (Y0 - 2);
      int sx0 = x0c - (X0 - 2), sx1 = x1c - (X0 - 2);
      sidx.x = (ushort)(sy0 * 12 + sx0);
      sidx.y = (ushort)(sy0 * 12 + sx1);
      sidx.z = (ushort)(sy1 * 12 + sx0);
      sidx.w = (ushort)(sy1 * 12 + sx1);
    } else {
      sidx.x = (ushort)((y0c * WD + x0c) | 0x8000);
      sidx.y = (ushort)(y0c * WD + x1c);
      sidx.z = (ushort)(y1c * WD + x0c);
      sidx.w = (ushort)(y1c * WD + x1c);
    }
    idxs[k][p] = sidx;
    ushort4 wc;
    wc.x = f2h(w0); wc.y = f2h(w1v); wc.z = f2h(w2); wc.w = f2h(w3);
    wgtc[k][p] = wc;
  }
  __syncthreads();

  int cc = t & 15;   // channel chunk (8 channels)
  int pp = t >> 4;   // 0..15; handles p = pp, pp+16
  int ct = w;        // wave = CO tile
  int pl = lane & 31, kh = lane >> 5;
  int pg = pl;
  f16x16 acc = (f16x16)(0.f);
  __half2 sa2v[4], sb2v[4];
#pragma unroll
  for (int j = 0; j < 4; ++j) { sa2v[j] = sah[cc * 4 + j]; sb2v[j] = sbh[cc * 4 + j]; }

  // prefetch residual x values (consumed in epilogue)
  int gp = (Y0 + (pg >> 3)) * 96 + X0 + (pg & 7);
  float xr[16];
#pragma unroll
  for (int reg = 0; reg < 16; ++reg) {
    int co = ct * 32 + 4 * kh + (reg & 3) + 8 * (reg >> 2);
    xr[reg] = x[(size_t)(b * 128 + co) * HWN + gp];
  }

  uint4 AW[8];
  for (int k = 0; k < 9; ++k) {
    const ushort* wk = wdp + (size_t)k * 16384;
#pragma unroll
    for (int ks = 0; ks < 8; ++ks)
      AW[ks] = *(const uint4*)(wk + (size_t)(ct * 8 + ks) * 512 + lane * 8);
    // blend from LDS halo (or rare global fallback) -> S[k&1]
    ushort* Sb_w = S[k & 1];
#pragma unroll
    for (int i2 = 0; i2 < 2; ++i2) {
      int p = pp + 16 * i2;
      ushort4 sidx = idxs[k][p];
      ushort4 wc = wgtc[k][p];
      uint4 C0, C1, C2, C3;
      if (sidx.x & 0x8000u) {
        C0 = gaffine(hb, sidx.x & 0x7fff, cc, sa2v, sb2v, c02);
        C1 = gaffine(hb, sidx.y, cc, sa2v, sb2v, c02);
        C2 = gaffine(hb, sidx.z, cc, sa2v, sb2v, c02);
        C3 = gaffine(hb, sidx.w, cc, sa2v, sb2v, c02);
      } else {
        C0 = *(const uint4*)&halo[sidx.x * 128 + ((cc ^ (sidx.x & 15)) * 8)];
        C1 = *(const uint4*)&halo[sidx.y * 128 + ((cc ^ (sidx.y & 15)) * 8)];
        C2 = *(const uint4*)&halo[sidx.z * 128 + ((cc ^ (sidx.z & 15)) * 8)];
        C3 = *(const uint4*)&halo[sidx.w * 128 + ((cc ^ (sidx.w & 15)) * 8)];
      }
      __half2 a0 = u2h((unsigned)wc.x * 0x10001u);
      __half2 a1 = u2h((unsigned)wc.y * 0x10001u);
      __half2 a2 = u2h((unsigned)wc.z * 0x10001u);
      __half2 a3 = u2h((unsigned)wc.w * 0x10001u);
      __half2 s0 = __hmul2(u2h(C0.x), a0);
      __half2 s1 = __hmul2(u2h(C0.y), a0);
      __half2 s2 = __hmul2(u2h(C0.z), a0);
      __half2 s3 = __hmul2(u2h(C0.w), a0);
      s0 = __hfma2(u2h(C1.x), a1, s0); s1 = __hfma2(u2h(C1.y), a1, s1);
      s2 = __hfma2(u2h(C1.z), a1, s2); s3 = __hfma2(u2h(C1.w), a1, s3);
      s0 = __hfma2(u2h(C2.x), a2, s0); s1 = __hfma2(u2h(C2.y), a2, s1);
      s2 = __hfma2(u2h(C2.z), a2, s2); s3 = __hfma2(u2h(C2.w), a2, s3);
      s0 = __hfma2(u2h(C3.x), a3, s0); s1 = __hfma2(u2h(C3.y), a3, s1);
      s2 = __hfma2(u2h(C3.z), a3, s2); s3 = __hfma2(u2h(C3.w), a3, s3);
      uint4 o4;
      o4.x = h2u(s0); o4.y = h2u(s1); o4.z = h2u(s2); o4.w = h2u(s3);
      *(uint4*)&Sb_w[p * 128 + ((cc ^ (p & 15)) * 8)] = o4;
    }
    asm volatile("s_waitcnt lgkmcnt(0)" ::: "memory");
    __builtin_amdgcn_s_barrier();
    // MFMA on S[k&1] (S[k&1] reuse fenced by the NEXT iteration's barrier)
    const ushort* Sb = S[k & 1];
    __builtin_amdgcn_s_setprio(1);
#pragma unroll
    for (int ks = 0; ks < 8; ++ks) {
      int u = (ks * 2 + kh) ^ (pg & 15);
      h8v bf = *(const h8v*)&Sb[pg * 128 + u * 8];
      acc = mfma32(u4h(AW[ks]), bf, acc);
    }
    __builtin_amdgcn_s_setprio(0);
  }
  // epilogue: residual + store (x already in regs)
#pragma unroll
  for (int reg = 0; reg < 16; ++reg) {
    int co = ct * 32 + 4 * kh + (reg & 3) + 8 * (reg >> 2);
    size_t oi = (size_t)(b * 128 + co) * HWN + gp;
    out[oi] = acc[reg] + xr[reg];
  }
}

extern "C" void kernel_launch(void* const* d_in, const int* in_sizes, int n_in,
                              void* d_out, int out_size, void* d_ws, size_t ws_size,
                              hipStream_t stream) {
  const float* x = (const float*)d_in[0];
  const float* g1 = (const float*)d_in[1];
  const float* b1 = (const float*)d_in[2];
  const float* g2 = (const float*)d_in[3];
  const float* b2 = (const float*)d_in[4];
  const float* w1 = (const float*)d_in[5];
  const float* bc1 = (const float*)d_in[6];
  const float* w_off = (const float*)d_in[7];
  const float* b_off = (const float*)d_in[8];
  const float* w_def = (const float*)d_in[9];
  float* out = (float*)d_out;
  float* ws = (float*)d_ws;

  // workspace layout (float units)
  ushort* w1p = (ushort*)ws;                   // 73728 f
  ushort* wofp = (ushort*)(ws + 73728);        // 18432 f
  ushort* wdp = (ushort*)(ws + 92160);         // 73728 f
  float* sa1 = ws + 165888;                    // 512
  float* sb1 = ws + 166400;                    // 512
  float* sa2 = ws + 166912;                    // 512
  float* sb2 = ws + 167424;                    // 512
  float* partS1 = ws + 167936;                 // 49152
  float* partQ1 = ws + 217088;                 // 49152
  float* partS2 = ws + 266240;                 // 32768
  float* partQ2 = ws + 299008;                 // 32768
  ushort* xh = (ushort*)(ws + 331776);         // 2359296 f (raw x, ch-minor f16)
  ushort* hBh = (ushort*)(ws + 2691072);       // 2359296 f (conv1 out raw, ch-minor f16)

  packxt_kernel<<<546, 256, 0, stream>>>(w1, w_def, w_off, x, w1p, wdp, wofp,
                                         (unsigned*)xh, partS1, partQ1);
  finalize_kernel<<<512, 64, 0, stream>>>(partS1, partQ1, g1, b1, sa1, sb1, 96);
  conv1_mfma<<<dim3(144, 4), 256, 0, stream>>>(xh, sa1, sb1, w1p, bc1, hBh);
  stats2_kernel<<<dim3(64, 4), 256, 0, stream>>>(hBh, partS2, partQ2);
  finalize_kernel<<<512, 64, 0, stream>>>(partS2, partQ2, g2, b2, sa2, sb2, 64);
  deform_fused<<<dim3(1152), 256, 0, stream>>>(hBh, sa2, sb2, wofp, b_off, wdp, x, out);
}